// Round 5
// baseline (351.727 us; speedup 1.0000x reference)
//
#include <hip/hip_runtime.h>

// Layer_Hist: per-row 30-bin histogram of x[4096, 16384] fp32.
//   bin = clip(floor((x-LO)/W), -1, 28) + 1  ==  floor(clamp(x*invW + 15, 0, 29))
//   out column order: [bin0, bin29, bin1..bin28]
//
// R5: A/B probe. Theories killed so far: LDS bank conflicts (R3, -5%),
// VGPR spills (R4, -2%). dur_us appears to carry ~245 us of harness
// restore/poison overhead (our kernel never shows in top-5; all rows are
// 160-us 1-GiB poison fills) -> kernel itself est. ~82 us vs 43 us HBM floor.
// This round: (a) DROP nontemporal (never A/B'd; may defeat L2 streaming),
// (b) kill the cur<-nxt register copy chain: fully unrolled 4-group loop with
// explicit A/B double buffer -> 4-8 float4 always in flight, no copies.
// LDS: transposed private counters h[bin*256+t] (bank=t%32, free 2-way,
// thread-exclusive -> no-return ds_add_u32, zero contention).

#define NBINS   30
#define THREADS 256
#define ROWLEN  16384
#define VPG     4                       // float4 per group per thread
#define GROUPS  (ROWLEN / 4 / THREADS / VPG)   // 4 groups

typedef float f4 __attribute__((ext_vector_type(4)));

__global__ __launch_bounds__(THREADS) void hist_kernel(
    const float* __restrict__ x, float* __restrict__ out)
{
    __shared__ unsigned int h[NBINS * THREADS];   // 30720 B
    __shared__ unsigned int partial[8 * NBINS];   //   960 B

    const int t   = threadIdx.x;
    const int row = blockIdx.x;

#pragma unroll
    for (int b = 0; b < NBINS; ++b) h[b * THREADS + t] = 0u;
    __syncthreads();

    const float invW = 28.0f / 12.0f;   // 2.3333333f
    const float c15  = 15.0f;           // 6*invW + 1 (bin offset folded in)

    const f4* xr = (const f4*)(x + (size_t)row * ROWLEN);

    f4 A[VPG], B[VPG];

#pragma unroll
    for (int j = 0; j < VPG; ++j) A[j] = xr[t + (0 * VPG + j) * THREADS];
#pragma unroll
    for (int j = 0; j < VPG; ++j) B[j] = xr[t + (1 * VPG + j) * THREADS];

    // process group 0 (A), prefetch group 2 into A, process 1 (B),
    // prefetch group 3 into B, process 2 (A), process 3 (B)
#pragma unroll
    for (int j = 0; j < VPG; ++j) {
        f4 v = A[j];
#pragma unroll
        for (int c = 0; c < 4; ++c) {
            int bin = __float2int_rd(fminf(fmaxf(fmaf(v[c], invW, c15), 0.0f), 29.0f));
            atomicAdd(&h[bin * THREADS + t], 1u);
        }
    }
#pragma unroll
    for (int j = 0; j < VPG; ++j) A[j] = xr[t + (2 * VPG + j) * THREADS];
#pragma unroll
    for (int j = 0; j < VPG; ++j) {
        f4 v = B[j];
#pragma unroll
        for (int c = 0; c < 4; ++c) {
            int bin = __float2int_rd(fminf(fmaxf(fmaf(v[c], invW, c15), 0.0f), 29.0f));
            atomicAdd(&h[bin * THREADS + t], 1u);
        }
    }
#pragma unroll
    for (int j = 0; j < VPG; ++j) B[j] = xr[t + (3 * VPG + j) * THREADS];
#pragma unroll
    for (int j = 0; j < VPG; ++j) {
        f4 v = A[j];
#pragma unroll
        for (int c = 0; c < 4; ++c) {
            int bin = __float2int_rd(fminf(fmaxf(fmaf(v[c], invW, c15), 0.0f), 29.0f));
            atomicAdd(&h[bin * THREADS + t], 1u);
        }
    }
#pragma unroll
    for (int j = 0; j < VPG; ++j) {
        f4 v = B[j];
#pragma unroll
        for (int c = 0; c < 4; ++c) {
            int bin = __float2int_rd(fminf(fmaxf(fmaf(v[c], invW, c15), 0.0f), 29.0f));
            atomicAdd(&h[bin * THREADS + t], 1u);
        }
    }
    __syncthreads();

    // Stage 1: 240 threads = 30 bins x 8 groups of 32 columns, rotated reads.
    if (t < 240) {
        const int b = t % NBINS;
        const int g = t / NBINS;
        unsigned int s = 0;
#pragma unroll
        for (int i = 0; i < 32; ++i)
            s += h[b * THREADS + g * 32 + ((i + b) & 31)];
        partial[g * NBINS + b] = s;
    }
    __syncthreads();

    // Stage 2: 30 threads sum 8 partials, reorder, store.
    if (t < NBINS) {
        unsigned int s = 0;
#pragma unroll
        for (int g = 0; g < 8; ++g) s += partial[g * NBINS + t];
        const int dst = (t == 0) ? 0 : (t == NBINS - 1) ? 1 : (t + 1);
        out[(size_t)row * NBINS + dst] = (float)s;
    }
}

extern "C" void kernel_launch(void* const* d_in, const int* in_sizes, int n_in,
                              void* d_out, int out_size, void* d_ws, size_t ws_size,
                              hipStream_t stream)
{
    const float* x  = (const float*)d_in[0];
    float* out      = (float*)d_out;
    const int rows  = in_sizes[0] / ROWLEN;   // 4096
    hist_kernel<<<rows, THREADS, 0, stream>>>(x, out);
}